// Round 8
// baseline (164.042 us; speedup 1.0000x reference)
//
#include <hip/hip_runtime.h>

// YOLOv1 loss, MI355X. Memory-bound streaming reduction — direct-load version.
// y_pred: (16384,7,7,30) f32, y_true: (16384,7,7,6) f32, out: scalar f32.
//
// Round-7 lesson: both LDS-staged structures (serial r1, async double-buffer
// r7) plateau at ~2.3 TB/s — the block-convoy + LDS round-trip is the
// limiter, and double-buffered LDS caps cell-parallelism at ~8 waves/CU.
// This version is the proven high-BW pattern (LN/RMSNorm-class): NO LDS, NO
// barriers, no inline asm. Each thread owns 2 cells = 240 B = exactly 15
// aligned float4 of y_pred + 3 float4 of y_true. Per-lane streams are
// diverged (240 B lane stride) but dense — every fetched byte is used, HBM
// traffic stays minimal, and 18 independent loads/thread x 16+ waves/CU
// gives massive MLP with zero synchronization.
// All register arrays use STATIC indexing only (argmax + label selects via
// unrolled ternary chains) — runtime indexing would go to scratch (r5 spill
// lesson: watch WRITE_SIZE; partials should be ~50 KB total).

#define CELLS    (16384 * 49)      // 802816
#define NTHREADS (CELLS / 2)       // 401408, 2 cells per thread
#define NBLK     (NTHREADS / 256)  // 1568, exact
#define LCOORD   5.0f
#define LNOOBJ   0.5f

__device__ __forceinline__ float iou_one(float x, float y, float w, float h,
                                         float t0, float t1, float t2, float t3) {
    float b1x1 = x - w * 0.5f, b1x2 = x + w * 0.5f;
    float b1y1 = y - h * 0.5f, b1y2 = y + h * 0.5f;
    float b2x1 = t0 - t2 * 0.5f, b2x2 = t0 + t2 * 0.5f;
    float b2y1 = t1 - t3 * 0.5f, b2y2 = t1 + t3 * 0.5f;
    float iw = fmaxf(fminf(b1x2, b2x2) - fmaxf(b1x1, b2x1), 0.0f);
    float ih = fmaxf(fminf(b1y2, b2y2) - fmaxf(b1y1, b2y1), 0.0f);
    float inter = iw * ih;
    float uni = w * h + t2 * t3 - inter;
    return inter / (uni + 1e-6f);
}

// One cell's loss contributions. p[30], t[6] are register arrays — every
// access below is a compile-time index (loops fully unrolled, runtime
// selects via ternary chains -> v_cndmask, never indexed loads).
__device__ __forceinline__ void cell_loss(const float (&p)[30], const float (&t)[6],
                                          float (&v)[6]) {
    float t0 = t[0], t1 = t[1], t2 = t[2], t3 = t[3], t4 = t[4];
    int lbl = (int)t[5];

    float iou0 = iou_one(p[0], p[1], p[2], p[3], t0, t1, t2, t3);
    float iou1 = iou_one(p[5], p[6], p[7], p[8], t0, t1, t2, t3);
    // jnp.argmax picks FIRST max on ties -> box1 wins only if strictly greater
    bool sel = (iou1 > iou0);
    float tb0 = sel ? p[5] : p[0];
    float tb1 = sel ? p[6] : p[1];
    float tb2 = sel ? p[7] : p[2];
    float tb3 = sel ? p[8] : p[3];
    float tb4 = sel ? p[9] : p[4];

    float obj = (t4 != 0.0f) ? 1.0f : 0.0f;
    float noobj = 1.0f - obj;

    float dx = tb0 - t0, dy = tb1 - t1;
    float a0 = obj * (dx * dx + dy * dy);

    float s2 = sqrtf(t2);              // reference uses y_true[...,2] for BOTH size terms
    float d2 = sqrtf(tb2) - s2;
    float d3 = sqrtf(tb3) - s2;
    float a1 = obj * (d2 * d2 + d3 * d3);

    float pc = fminf(fmaxf(tb4, 1e-7f), 1.0f - 1e-7f);
    float bce = -(t4 * logf(pc) + (1.0f - t4) * log1pf(-pc));
    float a2 = obj * bce;
    float a3 = noobj * bce;

    // log-softmax over 20 logits (p[10..29]), all-static indexing
    float m = p[10];
    #pragma unroll
    for (int c = 11; c < 30; ++c) m = fmaxf(m, p[c]);
    float se = 0.0f;
    #pragma unroll
    for (int c = 10; c < 30; ++c) se += expf(p[c] - m);
    float plbl = p[10];
    #pragma unroll
    for (int c = 1; c < 20; ++c) plbl = (lbl == c) ? p[10 + c] : plbl;
    float nll = logf(se) + m - plbl;
    float a4 = obj * nll;

    v[0] += a0; v[1] += a1; v[2] += a2; v[3] += a3; v[4] += a4; v[5] += obj;
}

__global__ __launch_bounds__(256, 1) void yolo_main(const float4* __restrict__ yp4,
                                                    const float4* __restrict__ yt4,
                                                    float* __restrict__ ws) {
    __shared__ float red[4][8];
    const int tid = threadIdx.x;
    const int gid = blockIdx.x * 256 + tid;

    // ---- load this thread's 2 cells: 15 + 3 float4, all 16B-aligned ----
    const float4* gp = yp4 + (size_t)gid * 15;
    float4 g[15];
    #pragma unroll
    for (int i = 0; i < 15; ++i) g[i] = gp[i];
    const float4* gt = yt4 + (size_t)gid * 3;
    float4 h0 = gt[0], h1 = gt[1], h2 = gt[2];

    // ---- unpack (pure register moves; static indices) ----
    float pA[30], pB[30], tA[6], tB[6];
    #pragma unroll
    for (int i = 0; i < 7; ++i) {
        pA[4 * i + 0] = g[i].x; pA[4 * i + 1] = g[i].y;
        pA[4 * i + 2] = g[i].z; pA[4 * i + 3] = g[i].w;
    }
    pA[28] = g[7].x; pA[29] = g[7].y;
    pB[0]  = g[7].z; pB[1]  = g[7].w;
    #pragma unroll
    for (int i = 0; i < 7; ++i) {
        pB[2 + 4 * i + 0] = g[8 + i].x; pB[2 + 4 * i + 1] = g[8 + i].y;
        pB[2 + 4 * i + 2] = g[8 + i].z; pB[2 + 4 * i + 3] = g[8 + i].w;
    }
    tA[0] = h0.x; tA[1] = h0.y; tA[2] = h0.z; tA[3] = h0.w;
    tA[4] = h1.x; tA[5] = h1.y;
    tB[0] = h1.z; tB[1] = h1.w;
    tB[2] = h2.x; tB[3] = h2.y; tB[4] = h2.z; tB[5] = h2.w;

    float v[6] = {0.f, 0.f, 0.f, 0.f, 0.f, 0.f};
    cell_loss(pA, tA, v);
    cell_loss(pB, tB, v);

    // ---- block reduce (4 waves) ----
    #pragma unroll
    for (int j = 0; j < 6; ++j) {
        #pragma unroll
        for (int off = 32; off > 0; off >>= 1)
            v[j] += __shfl_down(v[j], off, 64);
    }
    const int wave = tid >> 6, lane = tid & 63;
    if (lane == 0) {
        #pragma unroll
        for (int j = 0; j < 6; ++j) red[wave][j] = v[j];
    }
    __syncthreads();
    if (tid == 0) {
        float* dst = ws + (size_t)blockIdx.x * 8;
        #pragma unroll
        for (int j = 0; j < 6; ++j)
            dst[j] = red[0][j] + red[1][j] + red[2][j] + red[3][j];
    }
}

__global__ __launch_bounds__(256) void yolo_final(const float* __restrict__ ws,
                                                  float* __restrict__ out) {
    __shared__ float red[4][8];
    const int tid = threadIdx.x;
    float v[6] = {0.f, 0.f, 0.f, 0.f, 0.f, 0.f};
    for (int i = tid; i < NBLK; i += 256) {
        const float* src = ws + (size_t)i * 8;
        #pragma unroll
        for (int j = 0; j < 6; ++j) v[j] += src[j];
    }
    #pragma unroll
    for (int j = 0; j < 6; ++j) {
        #pragma unroll
        for (int off = 32; off > 0; off >>= 1)
            v[j] += __shfl_down(v[j], off, 64);
    }
    const int wave = tid >> 6, lane = tid & 63;
    if (lane == 0) {
        #pragma unroll
        for (int j = 0; j < 6; ++j) red[wave][j] = v[j];
    }
    __syncthreads();
    if (tid == 0) {
        float a[6];
        #pragma unroll
        for (int j = 0; j < 6; ++j)
            a[j] = red[0][j] + red[1][j] + red[2][j] + red[3][j];
        float n_obj = a[5];
        float n_noobj = (float)CELLS - n_obj;
        out[0] = (LCOORD * (a[0] + a[1]) + a[2] + a[4]) / n_obj
               + LNOOBJ * a[3] / n_noobj;
    }
}

extern "C" void kernel_launch(void* const* d_in, const int* in_sizes, int n_in,
                              void* d_out, int out_size, void* d_ws, size_t ws_size,
                              hipStream_t stream) {
    const float4* yp4 = (const float4*)d_in[0];  // (16384,7,7,30) = 6021120 float4
    const float4* yt4 = (const float4*)d_in[1];  // (16384,7,7,6)  = 1204224 float4
    float* out = (float*)d_out;
    float* ws = (float*)d_ws;   // needs 1568*8*4 = 50 KB

    yolo_main<<<NBLK, 256, 0, stream>>>(yp4, yt4, ws);
    yolo_final<<<1, 256, 0, stream>>>(ws, out);
}